// Round 1
// 442.946 us; speedup vs baseline: 1.0613x; 1.0613x over previous
//
#include <hip/hip_runtime.h>

// 8192x8192 fp32 -> per-8x8-block DCT-II, per-block inf-norm, int8 indices
// (stored as fp32). Output: [1024*1024*64 idx][1024*1024 biggest].
//
// R2 restructure: the thread-per-block version spilled (44 VGPRs vs a
// 64-float live set; WRITE_SIZE showed ~62 MB scratch traffic) and was
// latency-bound (VALUBusy 17%, HBM 32%, occupancy 45%).
// New shape: one 256-thread workgroup per 64x64-pixel tile (8x8 blocks of
// 8x8). Separable DCT split across threads with one LDS transpose:
//   Phase 1: thread owns two 8-px ROW segments -> 2x float4 coalesced
//            global load, row DCT (64 FMA w/ literal constants),
//            2x ds_write_b128 to padded LDS (stride 68 floats).
//   Phase 2: thread owns two 8-px block COLUMNS -> 8x ds_read_b32
//            (stride-68 column = exact 2-way banking = free), col DCT,
//            absmax via __shfl_xor within the 8-aligned lane group,
//            quantize, 8 scalar stores (each wave-store = eight full
//            32 B sectors -> no RMW at HBM).
// Live set ~24 floats/thread -> no spill possible. LDS 17408 B ->
// 8 workgroups/CU -> full thread-slot occupancy.

#define IMG_H 8192
#define IMG_W 8192
#define NB1 (IMG_H / 8)
#define NB2 (IMG_W / 8)
#define LSTR 68   // LDS row stride in floats: 64 + 4 pad (16B-aligned rows)

__global__ __launch_bounds__(256, 4) void dct_quant_kernel(
    const float* __restrict__ x,
    float* __restrict__ out_idx,   // NB1*NB2*64 floats
    float* __restrict__ out_big)   // NB1*NB2 floats
{
    // Orthonormal DCT-II matrix M[element][freq], fp32-exact constants.
    constexpr float k1 = 0.4903926402016152f;
    constexpr float k2 = 0.4619397662556434f;
    constexpr float k3 = 0.4157348061512726f;
    constexpr float k4 = 0.35355339059327373f;
    constexpr float k5 = 0.2777851165098011f;
    constexpr float k6 = 0.1913417161825449f;
    constexpr float k7 = 0.0975451610080642f;
    constexpr float M[8][8] = {
        { k4,  k1,  k2,  k3,  k4,  k5,  k6,  k7},
        { k4,  k3,  k6, -k7, -k4, -k1, -k2, -k5},
        { k4,  k5, -k6, -k1, -k4,  k7,  k2,  k3},
        { k4,  k7, -k2, -k5,  k4,  k3, -k6, -k1},
        { k4, -k7, -k2,  k5,  k4, -k3, -k6,  k1},
        { k4, -k5, -k6,  k1, -k4, -k7,  k2, -k3},
        { k4, -k3,  k6,  k7, -k4,  k1, -k2,  k5},
        { k4, -k1,  k2, -k3,  k4, -k5,  k6, -k7},
    };

    __shared__ float t1[64 * LSTR];

    const int t   = threadIdx.x;
    const int tb1 = blockIdx.x >> 7;    // tile row 0..127
    const int tb2 = blockIdx.x & 127;   // tile col 0..127

    const float* tile = x + (size_t)tb1 * 64 * IMG_W + (size_t)tb2 * 64;

    // ---------- Phase 1: row transform, global -> LDS ----------
    // Segment s (0..511): row = s>>3, blockcol = s&7. Thread t handles
    // s = t and s = t+256 (same blockcol, row+32).
    {
        const int r0 = t >> 3;
        const int c0 = t & 7;

        const float4* p0 = (const float4*)(tile + (size_t)r0 * IMG_W + c0 * 8);
        const float4* p1 = (const float4*)(tile + (size_t)(r0 + 32) * IMG_W + c0 * 8);
        // Issue all 4 loads up front.
        const float4 a0 = p0[0];
        const float4 a1 = p0[1];
        const float4 b0 = p1[0];
        const float4 b1 = p1[1];

        {
            const float u[8] = {a0.x, a0.y, a0.z, a0.w, a1.x, a1.y, a1.z, a1.w};
            float w[8];
#pragma unroll
            for (int h = 0; h < 8; ++h) {
                float s = u[0] * M[0][h];
#pragma unroll
                for (int f = 1; f < 8; ++f) s = fmaf(u[f], M[f][h], s);
                w[h] = s;
            }
            float* d = &t1[r0 * LSTR + c0 * 8];
            ((float4*)d)[0] = make_float4(w[0], w[1], w[2], w[3]);
            ((float4*)d)[1] = make_float4(w[4], w[5], w[6], w[7]);
        }
        {
            const float u[8] = {b0.x, b0.y, b0.z, b0.w, b1.x, b1.y, b1.z, b1.w};
            float w[8];
#pragma unroll
            for (int h = 0; h < 8; ++h) {
                float s = u[0] * M[0][h];
#pragma unroll
                for (int f = 1; f < 8; ++f) s = fmaf(u[f], M[f][h], s);
                w[h] = s;
            }
            float* d = &t1[(r0 + 32) * LSTR + c0 * 8];
            ((float4*)d)[0] = make_float4(w[0], w[1], w[2], w[3]);
            ((float4*)d)[1] = make_float4(w[4], w[5], w[6], w[7]);
        }
    }
    __syncthreads();

    // ---------- Phase 2: column transform, absmax, quantize, store ----------
    // Segment s (0..511): bb = s>>3 (block in tile), h = s&7 (freq column).
    // The 8 lanes of one block are contiguous and 8-aligned in lane space.
#pragma unroll
    for (int k = 0; k < 2; ++k) {
        const int s   = t + k * 256;
        const int bb  = s >> 3;
        const int h   = s & 7;
        const int bbr = bb >> 3;    // block row in tile
        const int bbc = bb & 7;     // block col in tile

        const float* col = &t1[bbr * 8 * LSTR + bbc * 8 + h];
        float v[8];
#pragma unroll
        for (int e = 0; e < 8; ++e) v[e] = col[e * LSTR];

        float c[8];
        float big = 0.0f;
#pragma unroll
        for (int g = 0; g < 8; ++g) {
            float s2 = M[0][g] * v[0];
#pragma unroll
            for (int e = 1; e < 8; ++e) s2 = fmaf(M[e][g], v[e], s2);
            c[g] = s2;
            big = fmaxf(big, fabsf(s2));
        }
        // Per-block inf-norm across the 8 column-owning lanes.
        big = fmaxf(big, __shfl_xor(big, 1));
        big = fmaxf(big, __shfl_xor(big, 2));
        big = fmaxf(big, __shfl_xor(big, 4));

        const float scale = 127.0f / big;
        const int b1 = tb1 * 8 + bbr;
        const int b2 = tb2 * 8 + bbc;
        const size_t blk = (size_t)b1 * NB2 + b2;

        float* o = out_idx + blk * 64 + h;
#pragma unroll
        for (int g = 0; g < 8; ++g) o[g * 8] = rintf(c[g] * scale);
        if (h == 0) out_big[blk] = big;
    }
}

extern "C" void kernel_launch(void* const* d_in, const int* in_sizes, int n_in,
                              void* d_out, int out_size, void* d_ws, size_t ws_size,
                              hipStream_t stream) {
    const float* x = (const float*)d_in[0];
    // d_in[1] (dct matrix) is a fixed function of BLOCK=8, hardcoded
    // fp32-identically in the kernel.
    float* out = (float*)d_out;
    float* out_idx = out;
    float* out_big = out + (size_t)NB1 * NB2 * 64;

    dct_quant_kernel<<<16384, 256, 0, stream>>>(x, out_idx, out_big);
}

// Round 3
// 439.616 us; speedup vs baseline: 1.0694x; 1.0076x over previous
//
#include <hip/hip_runtime.h>

// 8192x8192 fp32 -> per-8x8-block DCT-II, per-block inf-norm, int8 indices
// (stored as fp32). Output: [1024*1024*64 idx][1024*1024 biggest].
//
// R3/R4 structure (R3 bench was an infra failure — container died twice —
// so this is a resubmit of the audited kernel):
// the 8x8 transpose between the two separable DCT stages is done entirely
// in-register with 3-stage __shfl_xor butterflies (masks 1,2,4) inside an
// aligned 8-lane group (-> immediate-pattern ds_swizzle, no addr setup).
//   - 8 lanes of each lane-octet own the 8 ROWS of one 8x8 block
//   - row-DCT (64 FMA) -> transpose -> col-DCT (64 FMA) -> absmax
//     (3x shfl_xor, group-uniform) -> quantize -> transpose back
//   - each lane then holds a full coefficient ROW -> 2 contiguous float4
//     stores (vs 8 scattered scalars)
// Two independent segments per thread (loads hoisted) give ILP to hide the
// swizzle-chain latency. No LDS, no barriers -> occupancy limited only by
// VGPRs (~live set of ~24 floats).

#define IMG_H 8192
#define IMG_W 8192
#define NB1 (IMG_H / 8)
#define NB2 (IMG_W / 8)

// Orthonormal DCT-II matrix M[element][freq], fp32-exact constants.
__device__ __constant__ const float kM[8][8] = {
    { 0.35355339059327373f,  0.4903926402016152f,  0.4619397662556434f,
      0.4157348061512726f,  0.35355339059327373f,  0.2777851165098011f,
      0.1913417161825449f,  0.0975451610080642f },
    { 0.35355339059327373f,  0.4157348061512726f,  0.1913417161825449f,
     -0.0975451610080642f, -0.35355339059327373f, -0.4903926402016152f,
     -0.4619397662556434f, -0.2777851165098011f },
    { 0.35355339059327373f,  0.2777851165098011f, -0.1913417161825449f,
     -0.4903926402016152f, -0.35355339059327373f,  0.0975451610080642f,
      0.4619397662556434f,  0.4157348061512726f },
    { 0.35355339059327373f,  0.0975451610080642f, -0.4619397662556434f,
     -0.2777851165098011f,  0.35355339059327373f,  0.4157348061512726f,
     -0.1913417161825449f, -0.4903926402016152f },
    { 0.35355339059327373f, -0.0975451610080642f, -0.4619397662556434f,
      0.2777851165098011f,  0.35355339059327373f, -0.4157348061512726f,
     -0.1913417161825449f,  0.4903926402016152f },
    { 0.35355339059327373f, -0.2777851165098011f, -0.1913417161825449f,
      0.4903926402016152f, -0.35355339059327373f, -0.0975451610080642f,
      0.4619397662556434f, -0.4157348061512726f },
    { 0.35355339059327373f, -0.4157348061512726f,  0.1913417161825449f,
      0.0975451610080642f, -0.35355339059327373f,  0.4903926402016152f,
     -0.4619397662556434f,  0.2777851165098011f },
    { 0.35355339059327373f, -0.4903926402016152f,  0.4619397662556434f,
     -0.4157348061512726f,  0.35355339059327373f, -0.2777851165098011f,
      0.1913417161825449f, -0.0975451610080642f },
};

// 8x8 transpose distributed over 8 contiguous lanes (lane sub-index j),
// each lane holding 8 elements. 3-stage butterfly: stage m swaps bit m
// between the lane index and the register index. Element (j,g) moves to
// (j^m, g^m) iff bit m of j and g differ; one shfl serves both directions.
__device__ __forceinline__ void transpose8(float c[8], const int j) {
#pragma unroll
    for (int m = 1; m <= 4; m <<= 1) {
        const bool hi = (j & m) != 0;
#pragma unroll
        for (int g = 0; g < 8; ++g) {
            if ((g & m) == 0) {
                const float a = c[g];
                const float b = c[g + m];
                const float send = hi ? a : b;
                const float recv = __shfl_xor(send, m, 64);
                c[g]     = hi ? recv : a;
                c[g + m] = hi ? b : recv;
            }
        }
    }
}

// One segment: lane sub-index j owns row j of block `blk`; u = that row.
__device__ __forceinline__ void dct_block(float u[8], const int j,
                                          float* __restrict__ out_idx,
                                          float* __restrict__ out_big,
                                          const size_t blk) {
    // Row transform: w[h] = sum_f u[f] * M[f][h]
    float w[8];
#pragma unroll
    for (int h = 0; h < 8; ++h) {
        float s = u[0] * kM[0][h];
#pragma unroll
        for (int f = 1; f < 8; ++f) s = fmaf(u[f], kM[f][h], s);
        w[h] = s;
    }

    // Transpose: lane j now holds column j of T1 (w[e] = T1[e][j]).
    transpose8(w, j);

    // Column transform: c[g] = sum_e M[e][g] * T1[e][j]  -> C[g][j]
    float c[8];
    float big = 0.0f;
#pragma unroll
    for (int g = 0; g < 8; ++g) {
        float s = kM[0][g] * w[0];
#pragma unroll
        for (int e = 1; e < 8; ++e) s = fmaf(kM[e][g], w[e], s);
        c[g] = s;
        big = fmaxf(big, fabsf(s));
    }

    // Per-block inf-norm across the 8 column-owning lanes (group-uniform).
    big = fmaxf(big, __shfl_xor(big, 1, 64));
    big = fmaxf(big, __shfl_xor(big, 2, 64));
    big = fmaxf(big, __shfl_xor(big, 4, 64));

    // Quantize in place (jnp.round = half-to-even -> rintf).
    const float scale = 127.0f / big;
#pragma unroll
    for (int g = 0; g < 8; ++g) c[g] = rintf(c[g] * scale);

    // Transpose back: lane j now holds coefficient ROW j -> contiguous.
    transpose8(c, j);

    float* o = out_idx + blk * 64 + (size_t)j * 8;
    ((float4*)o)[0] = make_float4(c[0], c[1], c[2], c[3]);
    ((float4*)o)[1] = make_float4(c[4], c[5], c[6], c[7]);
    if (j == 0) out_big[blk] = big;
}

__global__ __launch_bounds__(256, 4) void dct_quant_kernel(
    const float* __restrict__ x,
    float* __restrict__ out_idx,   // NB1*NB2*64 floats
    float* __restrict__ out_big)   // NB1*NB2 floats
{
    const int t   = threadIdx.x;
    const int tb1 = blockIdx.x >> 7;    // tile row 0..127 (64-px bands)
    const int tb2 = blockIdx.x & 127;   // tile col 0..127

    const int j    = t & 7;          // row within block == lane sub-index
    const int bbc  = (t >> 3) & 7;   // block col within tile
    const int bbr0 = t >> 6;         // block row (segment 0); +4 for seg 1

    const float* tile = x + (size_t)tb1 * 64 * IMG_W + (size_t)tb2 * 64;

    // Hoist all global loads (2 segments x 2 float4).
    const float* r0 = tile + (size_t)(bbr0 * 8 + j) * IMG_W + bbc * 8;
    const float* r1 = r0 + (size_t)32 * IMG_W;
    const float4 a0 = ((const float4*)r0)[0];
    const float4 a1 = ((const float4*)r0)[1];
    const float4 b0 = ((const float4*)r1)[0];
    const float4 b1 = ((const float4*)r1)[1];

    const int b1_0 = tb1 * 8 + bbr0;
    const int b2   = tb2 * 8 + bbc;

    {
        float u[8] = {a0.x, a0.y, a0.z, a0.w, a1.x, a1.y, a1.z, a1.w};
        dct_block(u, j, out_idx, out_big, (size_t)b1_0 * NB2 + b2);
    }
    {
        float u[8] = {b0.x, b0.y, b0.z, b0.w, b1.x, b1.y, b1.z, b1.w};
        dct_block(u, j, out_idx, out_big, (size_t)(b1_0 + 4) * NB2 + b2);
    }
}

extern "C" void kernel_launch(void* const* d_in, const int* in_sizes, int n_in,
                              void* d_out, int out_size, void* d_ws, size_t ws_size,
                              hipStream_t stream) {
    const float* x = (const float*)d_in[0];
    // d_in[1] (dct matrix) is a fixed function of BLOCK=8, hardcoded
    // fp32-identically in the kernel.
    float* out = (float*)d_out;
    float* out_idx = out;
    float* out_big = out + (size_t)NB1 * NB2 * 64;

    dct_quant_kernel<<<16384, 256, 0, stream>>>(x, out_idx, out_big);
}